// Round 10
// baseline (828.909 us; speedup 1.0000x reference)
//
#include <hip/hip_runtime.h>
#include <hip/hip_bf16.h>

typedef short bf16x8 __attribute__((ext_vector_type(8)));
typedef float f32x4  __attribute__((ext_vector_type(4)));

#define NB    32
#define NH    128
#define DV    512
#define DQK   576
#define NKV   8192
#define NTOP  2048
#define LSTR  40          // LDS row stride in bf16 elems (32 data + 8 pad)
#define SCALE 0.041666666666666664f   // 1/sqrt(576)

// ---- replication factors (DIAGNOSTIC ONLY: duplicate idempotent work to surface kernels in rocprof top-5)
#define REP_QK 3
#define REP_SM 2
#define REP_PV 2
#define REP_R4 2

__device__ __forceinline__ unsigned bfbits(float x) {
  union { float f; unsigned u; } c; c.f = x;
  return (c.u + 0x7FFFu + ((c.u >> 16) & 1u)) >> 16;   // RNE; inputs never NaN
}
__device__ __forceinline__ unsigned pk2(float x, float y) {
  return bfbits(x) | (bfbits(y) << 16);
}
__device__ __forceinline__ short f2bf(float x) { return (short)bfbits(x); }

// ---------------- Kernel 1: S[b][h][k] = scale * Q[b][h][:] . KV[b][idx[k]][:]  (K=576) ----------------
__global__ __launch_bounds__(256) void gemm_qk(const float* __restrict__ Q, const float* __restrict__ KV,
                                               const int* __restrict__ Idx, float* __restrict__ S) {
  __shared__ short As[128 * LSTR];
  __shared__ short Bs[128 * LSTR];
  int wg = blockIdx.x % (NB * 16);        // replica = blockIdx.x / (NB*16): identical work, identical stores
  int b = wg >> 4, nt = wg & 15;          // 16 key-tiles of 128
  int t = threadIdx.x;

  int row2 = t >> 1, half = t & 1;
  int idx = Idx[b * NTOP + nt * 128 + row2];
  const float* kvrow = KV + ((size_t)b * NKV + (size_t)idx) * DQK + half * 16;
  const float* qrow  = Q  + ((size_t)b * NH  + (size_t)row2) * DQK + half * 16;
  short* aw = &As[row2 * LSTR + half * 16];
  short* bw = &Bs[row2 * LSTR + half * 16];

  int lane = t & 63, wv = t >> 6;
  int wm = wv & 1, wn = wv >> 1;          // 2x2 waves, 64x64 each
  int m16 = lane & 15, quad = lane >> 4;

  f32x4 acc[4][4] = {};

  float4 q0 = *(const float4*)(qrow + 0);
  float4 q1 = *(const float4*)(qrow + 4);
  float4 q2 = *(const float4*)(qrow + 8);
  float4 q3 = *(const float4*)(qrow + 12);
  float4 k0 = *(const float4*)(kvrow + 0);
  float4 k1 = *(const float4*)(kvrow + 4);
  float4 k2 = *(const float4*)(kvrow + 8);
  float4 k3 = *(const float4*)(kvrow + 12);

  for (int kk = 0; kk < 18; ++kk) {       // 576 / 32
    __syncthreads();
    int4 wa0 = { (int)pk2(q0.x, q0.y), (int)pk2(q0.z, q0.w), (int)pk2(q1.x, q1.y), (int)pk2(q1.z, q1.w) };
    int4 wa1 = { (int)pk2(q2.x, q2.y), (int)pk2(q2.z, q2.w), (int)pk2(q3.x, q3.y), (int)pk2(q3.z, q3.w) };
    int4 wb0 = { (int)pk2(k0.x, k0.y), (int)pk2(k0.z, k0.w), (int)pk2(k1.x, k1.y), (int)pk2(k1.z, k1.w) };
    int4 wb1 = { (int)pk2(k2.x, k2.y), (int)pk2(k2.z, k2.w), (int)pk2(k3.x, k3.y), (int)pk2(k3.z, k3.w) };
    *(int4*)aw = wa0; *(int4*)(aw + 8) = wa1;
    *(int4*)bw = wb0; *(int4*)(bw + 8) = wb1;
    __syncthreads();

    if (kk < 17) {
      qrow += 32; kvrow += 32;
      q0 = *(const float4*)(qrow + 0);
      q1 = *(const float4*)(qrow + 4);
      q2 = *(const float4*)(qrow + 8);
      q3 = *(const float4*)(qrow + 12);
      k0 = *(const float4*)(kvrow + 0);
      k1 = *(const float4*)(kvrow + 4);
      k2 = *(const float4*)(kvrow + 8);
      k3 = *(const float4*)(kvrow + 12);
    }

    bf16x8 af[4], bfr[4];
#pragma unroll
    for (int i = 0; i < 4; ++i) af[i]  = *(const bf16x8*)&As[(wm * 64 + i * 16 + m16) * LSTR + quad * 8];
#pragma unroll
    for (int j = 0; j < 4; ++j) bfr[j] = *(const bf16x8*)&Bs[(wn * 64 + j * 16 + m16) * LSTR + quad * 8];
#pragma unroll
    for (int i = 0; i < 4; ++i)
#pragma unroll
      for (int j = 0; j < 4; ++j)
        acc[i][j] = __builtin_amdgcn_mfma_f32_16x16x32_bf16(af[i], bfr[j], acc[i][j], 0, 0, 0);
  }

#pragma unroll
  for (int i = 0; i < 4; ++i)
#pragma unroll
    for (int j = 0; j < 4; ++j)
#pragma unroll
      for (int r = 0; r < 4; ++r) {
        int h = wm * 64 + i * 16 + quad * 4 + r;
        int n = nt * 128 + wn * 64 + j * 16 + m16;
        S[((size_t)b * NH + h) * NTOP + n] = acc[i][j][r] * SCALE;
      }
}

// ---------------- Kernel 2: rowwise softmax over 2048, write normalized bf16 P ----------------
__global__ __launch_bounds__(256) void softmax_k(const float* __restrict__ S, unsigned short* __restrict__ P) {
  int row = blockIdx.x % (NB * NH);        // replica duplicate: identical stores
  const float* s = S + (size_t)row * NTOP;
  unsigned short* p = P + (size_t)row * NTOP;
  int t = threadIdx.x;
  int lane = t & 63, wv = t >> 6;
  __shared__ float red[4];

  float4 v0 = *(const float4*)(s + t * 4);
  float4 v1 = *(const float4*)(s + 1024 + t * 4);

  float lm = fmaxf(fmaxf(fmaxf(v0.x, v0.y), fmaxf(v0.z, v0.w)),
                   fmaxf(fmaxf(v1.x, v1.y), fmaxf(v1.z, v1.w)));
  for (int off = 32; off > 0; off >>= 1) lm = fmaxf(lm, __shfl_down(lm, off));
  if (lane == 0) red[wv] = lm;
  __syncthreads();
  float m = fmaxf(fmaxf(red[0], red[1]), fmaxf(red[2], red[3]));

  float e0 = expf(v0.x - m), e1 = expf(v0.y - m), e2 = expf(v0.z - m), e3 = expf(v0.w - m);
  float e4 = expf(v1.x - m), e5 = expf(v1.y - m), e6 = expf(v1.z - m), e7 = expf(v1.w - m);
  float ls = ((e0 + e1) + (e2 + e3)) + ((e4 + e5) + (e6 + e7));
  for (int off = 32; off > 0; off >>= 1) ls += __shfl_down(ls, off);
  __syncthreads();
  if (lane == 0) red[wv] = ls;
  __syncthreads();
  float inv = 1.0f / (((red[0] + red[1]) + (red[2] + red[3])));

  uint2 o0 = { pk2(e0 * inv, e1 * inv), pk2(e2 * inv, e3 * inv) };
  uint2 o1 = { pk2(e4 * inv, e5 * inv), pk2(e6 * inv, e7 * inv) };
  *(uint2*)(p + t * 4) = o0;
  *(uint2*)(p + 1024 + t * 4) = o1;
}

// ---------------- Kernel 3: Pt[ks][b][h][d] = P . V (partial stores, idempotent; K-split x4) ----------------
__global__ __launch_bounds__(256) void gemm_pv(const unsigned short* __restrict__ P, const float* __restrict__ KV,
                                               const int* __restrict__ Idx, float* __restrict__ Pt) {
  __shared__ short As[128 * LSTR];          // P tile [128h][32k]
  __shared__ short Bt[128 * LSTR];          // V^T tile [128d][32k]
  int wg = blockIdx.x % (NB * 16);          // replica duplicate: identical stores
  int b = wg >> 4, nt = (wg >> 2) & 3, ks = wg & 3;
  int t = threadIdx.x;

  int arow = t >> 1, ahalf = t & 1;
  const unsigned short* prow = P + ((size_t)b * NH + arow) * NTOP + ks * 512 + ahalf * 16;
  short* aw = &As[arow * LSTR + ahalf * 16];

  int brow = t & 31;
  int bcol = (t >> 5) * 16;
  const int* idxp = Idx + b * NTOP + ks * 512 + brow;
  short* bw = &Bt[bcol * LSTR + brow];

  int lane = t & 63, wv = t >> 6;
  int wm = wv & 1, wn = wv >> 1;
  int m16 = lane & 15, quad = lane >> 4;

  f32x4 acc[4][4] = {};

  uint4 p0 = *(const uint4*)(prow);
  uint4 p1 = *(const uint4*)(prow + 8);
  int idx = idxp[0];
  const float* vrow = KV + ((size_t)b * NKV + (size_t)idx) * DQK + nt * 128 + bcol;
  float4 v0 = *(const float4*)(vrow + 0);
  float4 v1 = *(const float4*)(vrow + 4);
  float4 v2 = *(const float4*)(vrow + 8);
  float4 v3 = *(const float4*)(vrow + 12);

  for (int kk = 0; kk < 16; ++kk) {        // 512 / 32
    __syncthreads();
    *(uint4*)aw = p0; *(uint4*)(aw + 8) = p1;
    bw[0 * LSTR]  = f2bf(v0.x); bw[1 * LSTR]  = f2bf(v0.y); bw[2 * LSTR]  = f2bf(v0.z); bw[3 * LSTR]  = f2bf(v0.w);
    bw[4 * LSTR]  = f2bf(v1.x); bw[5 * LSTR]  = f2bf(v1.y); bw[6 * LSTR]  = f2bf(v1.z); bw[7 * LSTR]  = f2bf(v1.w);
    bw[8 * LSTR]  = f2bf(v2.x); bw[9 * LSTR]  = f2bf(v2.y); bw[10 * LSTR] = f2bf(v2.z); bw[11 * LSTR] = f2bf(v2.w);
    bw[12 * LSTR] = f2bf(v3.x); bw[13 * LSTR] = f2bf(v3.y); bw[14 * LSTR] = f2bf(v3.z); bw[15 * LSTR] = f2bf(v3.w);
    __syncthreads();

    if (kk < 15) {
      prow += 32;
      p0 = *(const uint4*)(prow);
      p1 = *(const uint4*)(prow + 8);
      int nidx = idxp[(kk + 1) * 32];
      const float* nv = KV + ((size_t)b * NKV + (size_t)nidx) * DQK + nt * 128 + bcol;
      v0 = *(const float4*)(nv + 0);
      v1 = *(const float4*)(nv + 4);
      v2 = *(const float4*)(nv + 8);
      v3 = *(const float4*)(nv + 12);
    }

    bf16x8 af[4], bfr[4];
#pragma unroll
    for (int i = 0; i < 4; ++i) af[i]  = *(const bf16x8*)&As[(wm * 64 + i * 16 + m16) * LSTR + quad * 8];
#pragma unroll
    for (int j = 0; j < 4; ++j) bfr[j] = *(const bf16x8*)&Bt[(wn * 64 + j * 16 + m16) * LSTR + quad * 8];
#pragma unroll
    for (int i = 0; i < 4; ++i)
#pragma unroll
      for (int j = 0; j < 4; ++j)
        acc[i][j] = __builtin_amdgcn_mfma_f32_16x16x32_bf16(af[i], bfr[j], acc[i][j], 0, 0, 0);
  }

  float* po = Pt + (size_t)ks * ((size_t)NB * NH * DV);
#pragma unroll
  for (int i = 0; i < 4; ++i)
#pragma unroll
    for (int j = 0; j < 4; ++j)
#pragma unroll
      for (int r = 0; r < 4; ++r) {
        int h = wm * 64 + i * 16 + quad * 4 + r;
        int d = nt * 128 + wn * 64 + j * 16 + m16;
        po[((size_t)b * NH + h) * DV + d] = acc[i][j][r];
      }
}

// ---------------- Kernel 4: Out = sum of 4 K-split partials (idempotent) ----------------
__global__ __launch_bounds__(256) void reduce4(const float* __restrict__ Pt, float* __restrict__ Out) {
  const size_t N = (size_t)NB * NH * DV;
  int blk = blockIdx.x % (int)(N / 1024);   // replica duplicate
  size_t i = ((size_t)blk * 256 + threadIdx.x) * 4;
  float4 a = *(const float4*)(Pt + i);
  float4 b = *(const float4*)(Pt + N + i);
  float4 c = *(const float4*)(Pt + 2 * N + i);
  float4 d = *(const float4*)(Pt + 3 * N + i);
  float4 o = { (a.x + b.x) + (c.x + d.x), (a.y + b.y) + (c.y + d.y),
               (a.z + b.z) + (c.z + d.z), (a.w + b.w) + (c.w + d.w) };
  *(float4*)(Out + i) = o;
}

extern "C" void kernel_launch(void* const* d_in, const int* in_sizes, int n_in,
                              void* d_out, int out_size, void* d_ws, size_t ws_size,
                              hipStream_t stream) {
  (void)in_sizes; (void)n_in; (void)ws_size; (void)out_size;
  const float* Q  = (const float*)d_in[0];
  const float* KV = (const float*)d_in[1];
  const int*  Idx = (const int*)d_in[2];
  float* Out = (float*)d_out;

  size_t szS = (size_t)NB * NH * NTOP * 4;                   // 33.55 MB
  float* S = (float*)d_ws;
  unsigned short* P = (unsigned short*)((char*)d_ws + szS);  // 16.78 MB
  float* Pt = (float*)((char*)d_ws + szS + (size_t)NB * NH * NTOP * 2);  // 4 partials, 67.11 MB

  gemm_qk<<<dim3(NB * 16 * REP_QK), dim3(256), 0, stream>>>(Q, KV, Idx, S);
  softmax_k<<<dim3(NB * NH * REP_SM), dim3(256), 0, stream>>>(S, P);
  gemm_pv<<<dim3(NB * 16 * REP_PV), dim3(256), 0, stream>>>(P, KV, Idx, Pt);
  reduce4<<<dim3((NB * NH * DV / 1024) * REP_R4), dim3(256), 0, stream>>>(Pt, Out);
}